// Round 6
// baseline (953.843 us; speedup 1.0000x reference)
//
#include <hip/hip_runtime.h>
#include <hip/hip_bf16.h>

#define NN 100000
#define EE 1000000
#define GG 128
#define NT 782               // node tiles of 128 (782*128 = 100096)
#define BN_EPS 1e-5f

// workspace float offsets
#define X_OFF     0L          // x row-major [NN][64]
#define T_OFF     6400000L    // tiled [NT][64][128] = 6,406,144 floats; PAIRS overlaps here pre-MLP
#define WT1_OFF   12806144L   // fh layer1 scaled cols [128][64]
#define C1_OFF    12814336L
#define WT2_OFF   12814400L   // fh layer2 scaled cols [64][64]
#define C2_OFF    12818496L
#define WTC1_OFF  12818560L   // conv layer1 x3
#define CC1_OFF   12830848L
#define WTC2_OFF  12831040L   // conv layer2 x3
#define CC2_OFF   12843328L
#define POOL_OFF  12843520L   // 4 stages * 128 * 64
#define CNT_OFF   12876288L   // 128
// int-typed views
#define COL_OFF   12876416L   // 1,000,000
#define CUR_OFF   13876416L   // 100,000
#define BSUM_OFF  13976416L   // 128
#define BCUR_OFF  13976544L   // 800

#define SCAN_BLK 1024
#define SCAN_NBLK ((NN + SCAN_BLK - 1) / SCAN_BLK)   // 98

// ---------------- prep: fold BN scale into weight columns ----------------
__global__ void prep_kernel(
    const float* __restrict__ fh_W1, const float* __restrict__ fh_b1, const float* __restrict__ fh_g1,
    const float* __restrict__ fh_bt1, const float* __restrict__ fh_m1, const float* __restrict__ fh_v1,
    const float* __restrict__ fh_W2, const float* __restrict__ fh_b2, const float* __restrict__ fh_g2,
    const float* __restrict__ fh_bt2, const float* __restrict__ fh_m2, const float* __restrict__ fh_v2,
    const float* __restrict__ cW1, const float* __restrict__ cb1, const float* __restrict__ cg1,
    const float* __restrict__ cbt1, const float* __restrict__ cm1, const float* __restrict__ cv1,
    const float* __restrict__ cW2, const float* __restrict__ cb2, const float* __restrict__ cg2,
    const float* __restrict__ cbt2, const float* __restrict__ cm2, const float* __restrict__ cv2,
    float* __restrict__ ws)
{
    int job = blockIdx.x;
    const float *W, *b, *g, *bt, *m, *v;
    float *Wo, *Co;
    int K;
    if (job == 0) {
        W = fh_W1; b = fh_b1; g = fh_g1; bt = fh_bt1; m = fh_m1; v = fh_v1;
        Wo = ws + WT1_OFF; Co = ws + C1_OFF; K = 128;
    } else if (job == 1) {
        W = fh_W2; b = fh_b2; g = fh_g2; bt = fh_bt2; m = fh_m2; v = fh_v2;
        Wo = ws + WT2_OFF; Co = ws + C2_OFF; K = 64;
    } else if (job <= 4) {
        int l = job - 2;
        W = cW1 + l * 4096; b = cb1 + l * 64; g = cg1 + l * 64; bt = cbt1 + l * 64;
        m = cm1 + l * 64; v = cv1 + l * 64;
        Wo = ws + WTC1_OFF + l * 4096; Co = ws + CC1_OFF + l * 64; K = 64;
    } else {
        int l = job - 5;
        W = cW2 + l * 4096; b = cb2 + l * 64; g = cg2 + l * 64; bt = cbt2 + l * 64;
        m = cm2 + l * 64; v = cv2 + l * 64;
        Wo = ws + WTC2_OFF + l * 4096; Co = ws + CC2_OFF + l * 64; K = 64;
    }
    int tot = 64 * K;
    for (int i = threadIdx.x; i < tot; i += blockDim.x) {
        int j = i & 63;
        float s = g[j] * rsqrtf(v[j] + BN_EPS);
        Wo[i] = W[i] * s;   // [k][j] layout, scale column j
    }
    if (threadIdx.x < 64) {
        int j = threadIdx.x;
        float s = g[j] * rsqrtf(v[j] + BN_EPS);
        Co[j] = (b[j] - m[j]) * s + bt[j];
    }
}

// ---------------- CSR build ----------------
__global__ __launch_bounds__(256) void hist_kernel(const int* __restrict__ edges, int* __restrict__ cnt)
{
    int e = blockIdx.x * blockDim.x + threadIdx.x;
    if (e >= EE) return;
    atomicAdd(&cnt[edges[EE + e]], 1);
}

__global__ __launch_bounds__(SCAN_BLK) void scan_pass1(const int* __restrict__ cnt, int* __restrict__ bsum)
{
    __shared__ int r[SCAN_BLK];
    int t = threadIdx.x;
    int i = blockIdx.x * SCAN_BLK + t;
    r[t] = (i < NN) ? cnt[i] : 0;
    __syncthreads();
    for (int off = SCAN_BLK / 2; off > 0; off >>= 1) {
        if (t < off) r[t] += r[t + off];
        __syncthreads();
    }
    if (t == 0) bsum[blockIdx.x] = r[0];
}

__global__ __launch_bounds__(128) void scan_pass2(int* __restrict__ bsum)
{
    __shared__ int s[128];
    int t = threadIdx.x;
    int v = (t < SCAN_NBLK) ? bsum[t] : 0;
    s[t] = v;
    __syncthreads();
    for (int off = 1; off < 128; off <<= 1) {
        int a = (t >= off) ? s[t - off] : 0;
        __syncthreads();
        s[t] += a;
        __syncthreads();
    }
    if (t < SCAN_NBLK) bsum[t] = s[t] - v;   // exclusive
}

__global__ __launch_bounds__(SCAN_BLK) void scan_pass3(int* __restrict__ cnt, const int* __restrict__ bsum)
{
    __shared__ int s[SCAN_BLK];
    int t = threadIdx.x;
    int i = blockIdx.x * SCAN_BLK + t;
    int v = (i < NN) ? cnt[i] : 0;
    s[t] = v;
    __syncthreads();
    for (int off = 1; off < SCAN_BLK; off <<= 1) {
        int a = (t >= off) ? s[t - off] : 0;
        __syncthreads();
        s[t] += a;
        __syncthreads();
    }
    if (i < NN) cnt[i] = bsum[blockIdx.x] + s[t] - v;   // exclusive start
}

// bucket cursors = node start of each 128-node bucket
__global__ void init_bcur_kernel(const int* __restrict__ cursor, int* __restrict__ bcur)
{
    int b = blockIdx.x * blockDim.x + threadIdx.x;
    if (b < NT) bcur[b] = cursor[b << 7];
}

// phase A: bucket edges by dst>>7, append (src,dst) pairs contiguously
__global__ __launch_bounds__(256) void fillA_kernel(
    const int* __restrict__ edges, int* __restrict__ bcur, uint2* __restrict__ pairs)
{
    int e = blockIdx.x * blockDim.x + threadIdx.x;
    if (e >= EE) return;
    int src = edges[e];
    int dst = edges[EE + e];
    int p = atomicAdd(&bcur[dst >> 7], 1);
    uint2 pr; pr.x = (unsigned)src; pr.y = (unsigned)dst;
    pairs[p] = pr;
}

// phase B: within-bucket scatter (cursor + col windows are L2-local)
__global__ __launch_bounds__(256) void fillB_kernel(
    const uint2* __restrict__ pairs, int* __restrict__ cursor, int* __restrict__ col)
{
    int p = blockIdx.x * blockDim.x + threadIdx.x;
    if (p >= EE) return;
    uint2 pr = pairs[p];
    int pos = atomicAdd(&cursor[pr.y], 1);
    col[pos] = (int)pr.x;
}
// after fillB: cursor[n] == row end; start = (n==0)?0:cursor[n-1]

// ---------------- gather: agg = x + sum x[src]; writes tiled T via LDS transpose ----------------
__global__ __launch_bounds__(256) void gather_t_kernel(
    const float* __restrict__ x, const int* __restrict__ cursor, const int* __restrict__ col,
    float* __restrict__ T)
{
    __shared__ float lds[64 * 65];
    int half = blockIdx.x & 1;
    int tile = blockIdx.x >> 1;
    int nbase = blockIdx.x << 6;
    int wv = threadIdx.x >> 6, lane = threadIdx.x & 63;
    int q = lane >> 4, c = lane & 15;
    const float4* x4 = (const float4*)x;
    for (int s = 0; s < 16; s++) {
        int i = wv * 16 + s;            // 0..63 within block
        int n = nbase + i;
        if (n < NN) {
            int st = (n == 0) ? 0 : cursor[n - 1];
            int en = cursor[n];
            float4 acc;
            if (q == 0) acc = x4[(long)n * 16 + c];
            else { acc.x = 0.f; acc.y = 0.f; acc.z = 0.f; acc.w = 0.f; }
            for (int b = st; b < en; b += 4) {
                int j = b + q;
                if (j < en) {
                    int sc = col[j];
                    float4 t = x4[(long)sc * 16 + c];
                    acc.x += t.x; acc.y += t.y; acc.z += t.z; acc.w += t.w;
                }
            }
            acc.x += __shfl_xor(acc.x, 16); acc.y += __shfl_xor(acc.y, 16);
            acc.z += __shfl_xor(acc.z, 16); acc.w += __shfl_xor(acc.w, 16);
            acc.x += __shfl_xor(acc.x, 32); acc.y += __shfl_xor(acc.y, 32);
            acc.z += __shfl_xor(acc.z, 32); acc.w += __shfl_xor(acc.w, 32);
            if (q == 0) {
                int f = c << 2;
                lds[(f + 0) * 65 + i] = acc.x;
                lds[(f + 1) * 65 + i] = acc.y;
                lds[(f + 2) * 65 + i] = acc.z;
                lds[(f + 3) * 65 + i] = acc.w;
            }
        }
    }
    __syncthreads();
    long gb = (long)tile * 8192 + (half << 6);
    for (int idx = threadIdx.x; idx < 4096; idx += 256) {
        int j = idx >> 6, i2 = idx & 63;
        T[gb + j * 128 + i2] = lds[j * 65 + i2];
    }
}

// ---------------- in-place tiled 64->64 layer + relu (thread = column) ----------------
__global__ __launch_bounds__(256) void mlp_t_kernel(
    float* T, const float* __restrict__ Ws, const float* __restrict__ Cv)
{
    int n = blockIdx.x * 256 + threadIdx.x;      // covers full padded tiles
    int tile = n >> 7, i = n & 127;
    float* base = T + (long)tile * 8192 + i;
    float a[64];
#pragma unroll
    for (int j = 0; j < 64; j++) a[j] = Cv[j];
    for (int k = 0; k < 64; k += 4) {
        float x0 = base[(k + 0) * 128];
        float x1 = base[(k + 1) * 128];
        float x2 = base[(k + 2) * 128];
        float x3 = base[(k + 3) * 128];
        const float* w = Ws + k * 64;
#pragma unroll
        for (int j = 0; j < 64; j++) a[j] += x0 * w[j];
#pragma unroll
        for (int j = 0; j < 64; j++) a[j] += x1 * w[64 + j];
#pragma unroll
        for (int j = 0; j < 64; j++) a[j] += x2 * w[128 + j];
#pragma unroll
        for (int j = 0; j < 64; j++) a[j] += x3 * w[192 + j];
    }
#pragma unroll
    for (int j = 0; j < 64; j++) base[j * 128] = fmaxf(a[j], 0.f);
}

// ---------------- tiled 64->64 layer + relu, output row-major x ----------------
__global__ __launch_bounds__(256) void mlp_t_out_kernel(
    const float* __restrict__ T, const float* __restrict__ Ws, const float* __restrict__ Cv,
    float* __restrict__ xout)
{
    int n = blockIdx.x * 256 + threadIdx.x;
    if (n >= NN) return;
    int tile = n >> 7, i = n & 127;
    const float* base = T + (long)tile * 8192 + i;
    float a[64];
#pragma unroll
    for (int j = 0; j < 64; j++) a[j] = Cv[j];
    for (int k = 0; k < 64; k += 4) {
        float x0 = base[(k + 0) * 128];
        float x1 = base[(k + 1) * 128];
        float x2 = base[(k + 2) * 128];
        float x3 = base[(k + 3) * 128];
        const float* w = Ws + k * 64;
#pragma unroll
        for (int j = 0; j < 64; j++) a[j] += x0 * w[j];
#pragma unroll
        for (int j = 0; j < 64; j++) a[j] += x1 * w[64 + j];
#pragma unroll
        for (int j = 0; j < 64; j++) a[j] += x2 * w[128 + j];
#pragma unroll
        for (int j = 0; j < 64; j++) a[j] += x3 * w[192 + j];
    }
    float4* o4 = (float4*)(xout + (long)n * 64);
#pragma unroll
    for (int q = 0; q < 16; q++) {
        float4 t;
        t.x = fmaxf(a[4*q+0], 0.f); t.y = fmaxf(a[4*q+1], 0.f);
        t.z = fmaxf(a[4*q+2], 0.f); t.w = fmaxf(a[4*q+3], 0.f);
        o4[q] = t;
    }
}

// ---------------- embedding gather + layer1, output tiled T ----------------
__global__ __launch_bounds__(256) void embed_l1_kernel(
    const int* __restrict__ node_ids, const float* __restrict__ emb,
    const float* __restrict__ Ws, const float* __restrict__ Cv,
    float* __restrict__ T)
{
    int n = blockIdx.x * 256 + threadIdx.x;
    if (n >= NN) return;
    long nid = node_ids[n];
    const float4* e4 = (const float4*)(emb + nid * 128);
    float a[64];
#pragma unroll
    for (int j = 0; j < 64; j++) a[j] = Cv[j];
#pragma unroll 4
    for (int q = 0; q < 32; q++) {
        float4 t = e4[q];
        const float* w = Ws + q * 256;
#pragma unroll
        for (int j = 0; j < 64; j++) a[j] += t.x * w[j];
#pragma unroll
        for (int j = 0; j < 64; j++) a[j] += t.y * w[64 + j];
#pragma unroll
        for (int j = 0; j < 64; j++) a[j] += t.z * w[128 + j];
#pragma unroll
        for (int j = 0; j < 64; j++) a[j] += t.w * w[192 + j];
    }
    int tile = n >> 7, i = n & 127;
    float* base = T + (long)tile * 8192 + i;
#pragma unroll
    for (int j = 0; j < 64; j++) base[j * 128] = fmaxf(a[j], 0.f);
}

// ---------------- graph pooling over sorted batch (wave per node range) ----------------
#define POOL_WAVES 4096
#define POOL_CHUNK ((NN + POOL_WAVES - 1) / POOL_WAVES)
__global__ __launch_bounds__(256) void pool_kernel(
    const float* __restrict__ x, const int* __restrict__ batch,
    float* __restrict__ pooled, float* __restrict__ cnt)
{
    int wave = (blockIdx.x * blockDim.x + threadIdx.x) >> 6;
    int lane = threadIdx.x & 63;
    int start = wave * POOL_CHUNK;
    int end = start + POOL_CHUNK;
    if (end > NN) end = NN;
    if (start >= end) return;
    int g_cur = batch[start];
    float acc = 0.f, c = 0.f;
    for (int n = start; n < end; ++n) {
        int g = batch[n];
        if (g != g_cur) {
            unsafeAtomicAdd(&pooled[(long)g_cur * 64 + lane], acc);
            if (cnt != nullptr && lane == 0) unsafeAtomicAdd(&cnt[g_cur], c);
            acc = 0.f; c = 0.f; g_cur = g;
        }
        acc += x[(long)n * 64 + lane];
        c += 1.f;
    }
    unsafeAtomicAdd(&pooled[(long)g_cur * 64 + lane], acc);
    if (cnt != nullptr && lane == 0) unsafeAtomicAdd(&cnt[g_cur], c);
}

// ---------------- readout + softmax ----------------
__global__ void final_kernel(
    const float* __restrict__ pooled, const float* __restrict__ cnt,
    const float* __restrict__ linW, const float* __restrict__ linb,
    float* __restrict__ outp)
{
    int g = threadIdx.x;
    if (g >= GG) return;
    float z0 = 0.f, z1 = 0.f;
    float c = cnt[g];
    for (int l = 0; l < 4; l++) {
        const float* p = pooled + (long)l * GG * 64 + (long)g * 64;
        const float* W = linW + l * 128;
        float bscale = (l == 0) ? c : 1.f;
        float s0 = linb[l * 2 + 0] * bscale;
        float s1 = linb[l * 2 + 1] * bscale;
        for (int k = 0; k < 64; k++) {
            float pk = p[k];
            s0 += pk * W[k * 2 + 0];
            s1 += pk * W[k * 2 + 1];
        }
        z0 += s0; z1 += s1;
    }
    float mx = fmaxf(z0, z1);
    float e0 = expf(z0 - mx), e1 = expf(z1 - mx);
    float inv = 1.f / (e0 + e1);
    outp[g * 2 + 0] = e0 * inv;
    outp[g * 2 + 1] = e1 * inv;
}

extern "C" void kernel_launch(void* const* d_in, const int* in_sizes, int n_in,
                              void* d_out, int out_size, void* d_ws, size_t ws_size,
                              hipStream_t stream) {
    const int*   node_ids = (const int*)d_in[0];
    const int*   edges    = (const int*)d_in[1];
    const int*   batch    = (const int*)d_in[2];
    const float* emb      = (const float*)d_in[3];
    const float* fh_W1 = (const float*)d_in[4];
    const float* fh_b1 = (const float*)d_in[5];
    const float* fh_g1 = (const float*)d_in[6];
    const float* fh_bt1 = (const float*)d_in[7];
    const float* fh_m1 = (const float*)d_in[8];
    const float* fh_v1 = (const float*)d_in[9];
    const float* fh_W2 = (const float*)d_in[10];
    const float* fh_b2 = (const float*)d_in[11];
    const float* fh_g2 = (const float*)d_in[12];
    const float* fh_bt2 = (const float*)d_in[13];
    const float* fh_m2 = (const float*)d_in[14];
    const float* fh_v2 = (const float*)d_in[15];
    const float* cW1 = (const float*)d_in[16];
    const float* cb1 = (const float*)d_in[17];
    const float* cg1 = (const float*)d_in[18];
    const float* cbt1 = (const float*)d_in[19];
    const float* cm1 = (const float*)d_in[20];
    const float* cv1 = (const float*)d_in[21];
    const float* cW2 = (const float*)d_in[22];
    const float* cb2 = (const float*)d_in[23];
    const float* cg2 = (const float*)d_in[24];
    const float* cbt2 = (const float*)d_in[25];
    const float* cm2 = (const float*)d_in[26];
    const float* cv2 = (const float*)d_in[27];
    const float* linW = (const float*)d_in[28];
    const float* linb = (const float*)d_in[29];

    float* ws = (float*)d_ws;
    int*   cursor = (int*)(ws + CUR_OFF);
    int*   col    = (int*)(ws + COL_OFF);
    int*   bsum   = (int*)(ws + BSUM_OFF);
    int*   bcur   = (int*)(ws + BCUR_OFF);
    uint2* pairs  = (uint2*)(ws + T_OFF);     // overlaps T; dead before first T write
    float* Tt     = ws + T_OFF;

    prep_kernel<<<8, 256, 0, stream>>>(
        fh_W1, fh_b1, fh_g1, fh_bt1, fh_m1, fh_v1,
        fh_W2, fh_b2, fh_g2, fh_bt2, fh_m2, fh_v2,
        cW1, cb1, cg1, cbt1, cm1, cv1,
        cW2, cb2, cg2, cbt2, cm2, cv2, ws);

    hipMemsetAsync(ws + POOL_OFF, 0, (4L * GG * 64 + GG) * sizeof(float), stream);
    hipMemsetAsync(cursor, 0, NN * sizeof(int), stream);

    // CSR build (dst-indexed, bucketed two-phase fill)
    hist_kernel<<<(EE + 255) / 256, 256, 0, stream>>>(edges, cursor);
    scan_pass1<<<SCAN_NBLK, SCAN_BLK, 0, stream>>>(cursor, bsum);
    scan_pass2<<<1, 128, 0, stream>>>(bsum);
    scan_pass3<<<SCAN_NBLK, SCAN_BLK, 0, stream>>>(cursor, bsum);
    init_bcur_kernel<<<(NT + 255) / 256, 256, 0, stream>>>(cursor, bcur);
    fillA_kernel<<<(EE + 255) / 256, 256, 0, stream>>>(edges, bcur, pairs);
    fillB_kernel<<<(EE + 255) / 256, 256, 0, stream>>>(pairs, cursor, col);

    const int MBLK = (NT * 128) / 256;   // 391

    // first MLP: emb + L1 -> T (tiled), then L2: T -> x (row-major)
    embed_l1_kernel<<<MBLK, 256, 0, stream>>>(
        node_ids, emb, ws + WT1_OFF, ws + C1_OFF, Tt);
    mlp_t_out_kernel<<<MBLK, 256, 0, stream>>>(
        Tt, ws + WT2_OFF, ws + C2_OFF, ws + X_OFF);

    pool_kernel<<<POOL_WAVES / 4, 256, 0, stream>>>(
        ws + X_OFF, batch, ws + POOL_OFF, ws + CNT_OFF);

    for (int l = 0; l < 3; l++) {
        gather_t_kernel<<<NT * 2, 256, 0, stream>>>(ws + X_OFF, cursor, col, Tt);
        mlp_t_kernel<<<MBLK, 256, 0, stream>>>(
            Tt, ws + WTC1_OFF + l * 4096, ws + CC1_OFF + l * 64);
        mlp_t_out_kernel<<<MBLK, 256, 0, stream>>>(
            Tt, ws + WTC2_OFF + l * 4096, ws + CC2_OFF + l * 64, ws + X_OFF);
        pool_kernel<<<POOL_WAVES / 4, 256, 0, stream>>>(
            ws + X_OFF, batch, ws + POOL_OFF + (long)(l + 1) * GG * 64, nullptr);
    }

    final_kernel<<<1, 128, 0, stream>>>(
        ws + POOL_OFF, ws + CNT_OFF, linW, linb, (float*)d_out);
}

// Round 7
// 686.171 us; speedup vs baseline: 1.3901x; 1.3901x over previous
//
#include <hip/hip_runtime.h>
#include <hip/hip_bf16.h>

#define NN 100000
#define EE 1000000
#define GG 128
#define NT 782               // node tiles of 128 (782*128 = 100096)
#define BN_EPS 1e-5f

// workspace float offsets
#define X_OFF     0L          // x row-major [NN][64]
#define T_OFF     6400000L    // tiled [NT][64][128]
#define WT1_OFF   12806144L   // fh layer1 scaled cols [128][64]
#define C1_OFF    12814336L
#define WT2_OFF   12814400L   // fh layer2 scaled cols [64][64]
#define C2_OFF    12818496L
#define WTC1_OFF  12818560L   // conv layer1 x3
#define CC1_OFF   12830848L
#define WTC2_OFF  12831040L   // conv layer2 x3
#define CC2_OFF   12843328L
#define POOL_OFF  12843520L   // 4 stages * 128 * 64
#define CNT_OFF   12876288L   // 128
// int-typed views
#define COL_OFF   12876416L   // 1,000,000
#define CUR_OFF   13876416L   // 100,000
#define BSUM_OFF  13976416L   // 128

#define SCAN_BLK 1024
#define SCAN_NBLK ((NN + SCAN_BLK - 1) / SCAN_BLK)   // 98

// ---------------- prep: fold BN scale into weight columns ----------------
__global__ void prep_kernel(
    const float* __restrict__ fh_W1, const float* __restrict__ fh_b1, const float* __restrict__ fh_g1,
    const float* __restrict__ fh_bt1, const float* __restrict__ fh_m1, const float* __restrict__ fh_v1,
    const float* __restrict__ fh_W2, const float* __restrict__ fh_b2, const float* __restrict__ fh_g2,
    const float* __restrict__ fh_bt2, const float* __restrict__ fh_m2, const float* __restrict__ fh_v2,
    const float* __restrict__ cW1, const float* __restrict__ cb1, const float* __restrict__ cg1,
    const float* __restrict__ cbt1, const float* __restrict__ cm1, const float* __restrict__ cv1,
    const float* __restrict__ cW2, const float* __restrict__ cb2, const float* __restrict__ cg2,
    const float* __restrict__ cbt2, const float* __restrict__ cm2, const float* __restrict__ cv2,
    float* __restrict__ ws)
{
    int job = blockIdx.x;
    const float *W, *b, *g, *bt, *m, *v;
    float *Wo, *Co;
    int K;
    if (job == 0) {
        W = fh_W1; b = fh_b1; g = fh_g1; bt = fh_bt1; m = fh_m1; v = fh_v1;
        Wo = ws + WT1_OFF; Co = ws + C1_OFF; K = 128;
    } else if (job == 1) {
        W = fh_W2; b = fh_b2; g = fh_g2; bt = fh_bt2; m = fh_m2; v = fh_v2;
        Wo = ws + WT2_OFF; Co = ws + C2_OFF; K = 64;
    } else if (job <= 4) {
        int l = job - 2;
        W = cW1 + l * 4096; b = cb1 + l * 64; g = cg1 + l * 64; bt = cbt1 + l * 64;
        m = cm1 + l * 64; v = cv1 + l * 64;
        Wo = ws + WTC1_OFF + l * 4096; Co = ws + CC1_OFF + l * 64; K = 64;
    } else {
        int l = job - 5;
        W = cW2 + l * 4096; b = cb2 + l * 64; g = cg2 + l * 64; bt = cbt2 + l * 64;
        m = cm2 + l * 64; v = cv2 + l * 64;
        Wo = ws + WTC2_OFF + l * 4096; Co = ws + CC2_OFF + l * 64; K = 64;
    }
    int tot = 64 * K;
    for (int i = threadIdx.x; i < tot; i += blockDim.x) {
        int j = i & 63;
        float s = g[j] * rsqrtf(v[j] + BN_EPS);
        Wo[i] = W[i] * s;   // [k][j] layout, scale column j
    }
    if (threadIdx.x < 64) {
        int j = threadIdx.x;
        float s = g[j] * rsqrtf(v[j] + BN_EPS);
        Co[j] = (b[j] - m[j]) * s + bt[j];
    }
}

// ---------------- CSR build ----------------
__global__ __launch_bounds__(256) void hist_kernel(const int* __restrict__ edges, int* __restrict__ cnt)
{
    int e = blockIdx.x * blockDim.x + threadIdx.x;
    if (e >= EE) return;
    atomicAdd(&cnt[edges[EE + e]], 1);
}

__global__ __launch_bounds__(SCAN_BLK) void scan_pass1(const int* __restrict__ cnt, int* __restrict__ bsum)
{
    __shared__ int r[SCAN_BLK];
    int t = threadIdx.x;
    int i = blockIdx.x * SCAN_BLK + t;
    r[t] = (i < NN) ? cnt[i] : 0;
    __syncthreads();
    for (int off = SCAN_BLK / 2; off > 0; off >>= 1) {
        if (t < off) r[t] += r[t + off];
        __syncthreads();
    }
    if (t == 0) bsum[blockIdx.x] = r[0];
}

__global__ __launch_bounds__(128) void scan_pass2(int* __restrict__ bsum)
{
    __shared__ int s[128];
    int t = threadIdx.x;
    int v = (t < SCAN_NBLK) ? bsum[t] : 0;
    s[t] = v;
    __syncthreads();
    for (int off = 1; off < 128; off <<= 1) {
        int a = (t >= off) ? s[t - off] : 0;
        __syncthreads();
        s[t] += a;
        __syncthreads();
    }
    if (t < SCAN_NBLK) bsum[t] = s[t] - v;   // exclusive
}

__global__ __launch_bounds__(SCAN_BLK) void scan_pass3(int* __restrict__ cnt, const int* __restrict__ bsum)
{
    __shared__ int s[SCAN_BLK];
    int t = threadIdx.x;
    int i = blockIdx.x * SCAN_BLK + t;
    int v = (i < NN) ? cnt[i] : 0;
    s[t] = v;
    __syncthreads();
    for (int off = 1; off < SCAN_BLK; off <<= 1) {
        int a = (t >= off) ? s[t - off] : 0;
        __syncthreads();
        s[t] += a;
        __syncthreads();
    }
    if (i < NN) cnt[i] = bsum[blockIdx.x] + s[t] - v;   // exclusive start
}

__global__ __launch_bounds__(256) void fill_kernel(
    const int* __restrict__ edges, int* __restrict__ cursor, int* __restrict__ col)
{
    int e = blockIdx.x * blockDim.x + threadIdx.x;
    if (e >= EE) return;
    int dst = edges[EE + e];
    int p = atomicAdd(&cursor[dst], 1);
    col[p] = edges[e];
}
// after fill: cursor[n] == row end; start = (n==0)?0:cursor[n-1]

// ---------------- gather: agg = x + sum x[src]; 8 rows in flight; writes tiled T ----------------
__global__ __launch_bounds__(256) void gather_t_kernel(
    const float* __restrict__ x, const int* __restrict__ cursor, const int* __restrict__ col,
    float* __restrict__ T)
{
    __shared__ float lds[64 * 65];
    int half = blockIdx.x & 1;
    int tile = blockIdx.x >> 1;
    int nbase = blockIdx.x << 6;
    int wv = threadIdx.x >> 6, lane = threadIdx.x & 63;
    int q = lane >> 3, c = lane & 7;   // 8 neighbor slots x 8 float4-columns
    const float4* x4 = (const float4*)x;
    for (int s = 0; s < 16; s++) {
        int i = wv * 16 + s;            // 0..63 within block
        int n = nbase + i;
        if (n < NN) {
            int st = (n == 0) ? 0 : cursor[n - 1];
            int en = cursor[n];
            float4 a0, a1;
            if (q == 0) { a0 = x4[(long)n * 16 + c]; a1 = x4[(long)n * 16 + 8 + c]; }
            else {
                a0.x = 0.f; a0.y = 0.f; a0.z = 0.f; a0.w = 0.f;
                a1.x = 0.f; a1.y = 0.f; a1.z = 0.f; a1.w = 0.f;
            }
            for (int b = st; b < en; b += 8) {
                int j = b + q;
                if (j < en) {
                    int sc = col[j];
                    float4 t0 = x4[(long)sc * 16 + c];
                    float4 t1 = x4[(long)sc * 16 + 8 + c];
                    a0.x += t0.x; a0.y += t0.y; a0.z += t0.z; a0.w += t0.w;
                    a1.x += t1.x; a1.y += t1.y; a1.z += t1.z; a1.w += t1.w;
                }
            }
#pragma unroll
            for (int d = 8; d <= 32; d <<= 1) {
                a0.x += __shfl_xor(a0.x, d); a0.y += __shfl_xor(a0.y, d);
                a0.z += __shfl_xor(a0.z, d); a0.w += __shfl_xor(a0.w, d);
                a1.x += __shfl_xor(a1.x, d); a1.y += __shfl_xor(a1.y, d);
                a1.z += __shfl_xor(a1.z, d); a1.w += __shfl_xor(a1.w, d);
            }
            if (q == 0) {
                int f0 = c << 2, f1 = 32 + (c << 2);
                lds[(f0 + 0) * 65 + i] = a0.x;
                lds[(f0 + 1) * 65 + i] = a0.y;
                lds[(f0 + 2) * 65 + i] = a0.z;
                lds[(f0 + 3) * 65 + i] = a0.w;
                lds[(f1 + 0) * 65 + i] = a1.x;
                lds[(f1 + 1) * 65 + i] = a1.y;
                lds[(f1 + 2) * 65 + i] = a1.z;
                lds[(f1 + 3) * 65 + i] = a1.w;
            }
        }
    }
    __syncthreads();
    long gb = (long)tile * 8192 + (half << 6);
    for (int idx = threadIdx.x; idx < 4096; idx += 256) {
        int j = idx >> 6, i2 = idx & 63;
        T[gb + j * 128 + i2] = lds[j * 65 + i2];
    }
}

// ---------------- in-place tiled 64->64 layer + relu (thread = column) ----------------
__global__ __launch_bounds__(256) void mlp_t_kernel(
    float* T, const float* __restrict__ Ws, const float* __restrict__ Cv)
{
    int n = blockIdx.x * 256 + threadIdx.x;      // covers padded tiles
    int tile = n >> 7, i = n & 127;
    float* base = T + (long)tile * 8192 + i;
    float a[64];
#pragma unroll
    for (int j = 0; j < 64; j++) a[j] = Cv[j];
    for (int k = 0; k < 64; k += 4) {
        float x0 = base[(k + 0) * 128];
        float x1 = base[(k + 1) * 128];
        float x2 = base[(k + 2) * 128];
        float x3 = base[(k + 3) * 128];
        const float* w = Ws + k * 64;
#pragma unroll
        for (int j = 0; j < 64; j++) a[j] += x0 * w[j];
#pragma unroll
        for (int j = 0; j < 64; j++) a[j] += x1 * w[64 + j];
#pragma unroll
        for (int j = 0; j < 64; j++) a[j] += x2 * w[128 + j];
#pragma unroll
        for (int j = 0; j < 64; j++) a[j] += x3 * w[192 + j];
    }
#pragma unroll
    for (int j = 0; j < 64; j++) base[j * 128] = fmaxf(a[j], 0.f);
}

// ---------------- tiled 64->64 layer + relu -> x, with FUSED graph pooling ----------------
__global__ __launch_bounds__(256) void mlp_t_out_pool_kernel(
    const float* __restrict__ T, const float* __restrict__ Ws, const float* __restrict__ Cv,
    const int* __restrict__ batch, float* __restrict__ xout,
    float* __restrict__ pooled, float* __restrict__ cnt)
{
    __shared__ float lds[4 * 16 * 65];
    int n = blockIdx.x * 256 + threadIdx.x;
    int lane = threadIdx.x & 63, wv = threadIdx.x >> 6;
    bool valid = n < NN;
    float a[64];
    if (valid) {
        int tile = n >> 7, i = n & 127;
        const float* base = T + (long)tile * 8192 + i;
#pragma unroll
        for (int j = 0; j < 64; j++) a[j] = Cv[j];
        for (int k = 0; k < 64; k += 4) {
            float x0 = base[(k + 0) * 128];
            float x1 = base[(k + 1) * 128];
            float x2 = base[(k + 2) * 128];
            float x3 = base[(k + 3) * 128];
            const float* w = Ws + k * 64;
#pragma unroll
            for (int j = 0; j < 64; j++) a[j] += x0 * w[j];
#pragma unroll
            for (int j = 0; j < 64; j++) a[j] += x1 * w[64 + j];
#pragma unroll
            for (int j = 0; j < 64; j++) a[j] += x2 * w[128 + j];
#pragma unroll
            for (int j = 0; j < 64; j++) a[j] += x3 * w[192 + j];
        }
#pragma unroll
        for (int j = 0; j < 64; j++) a[j] = fmaxf(a[j], 0.f);
        float4* o4 = (float4*)(xout + (long)n * 64);
#pragma unroll
        for (int qd = 0; qd < 16; qd++) {
            float4 t;
            t.x = a[4*qd+0]; t.y = a[4*qd+1]; t.z = a[4*qd+2]; t.w = a[4*qd+3];
            o4[qd] = t;
        }
    } else {
#pragma unroll
        for (int j = 0; j < 64; j++) a[j] = 0.f;
    }

    // ---- fused pooling: per-wave LDS transpose + run-segmented reduce ----
    int b = valid ? batch[n] : -1;
    int bprev = __shfl(b, (lane == 0) ? 0 : lane - 1);
    bool bound = (lane == 0) || (b != bprev);
    unsigned long long m = __ballot(bound);
    float* wbase = lds + wv * 1040;   // 16*65 per wave
    int f = lane & 15, qq = lane >> 4;
    for (int fc = 0; fc < 4; fc++) {
#pragma unroll
        for (int ff = 0; ff < 16; ff++) wbase[ff * 65 + lane] = a[fc * 16 + ff];
        __syncthreads();
        const float* src = wbase + f * 65 + qq * 16;
        int p = 0;
        while (p < 64) {
            unsigned long long rest = (p < 63) ? (m & (~0ULL << (p + 1))) : 0ULL;
            int np = rest ? (__ffsll((long long)rest) - 1) : 64;
            int g = __shfl(b, p);
            if (g >= 0) {
                float s = 0.f;
                for (int k = 0; k < 16; k++) {
                    int kk = qq * 16 + k;
                    if (kk >= p && kk < np) s += src[k];
                }
                s += __shfl_xor(s, 16);
                s += __shfl_xor(s, 32);
                if (qq == 0) unsafeAtomicAdd(&pooled[g * 64 + fc * 16 + f], s);
                if (cnt != nullptr && fc == 0 && lane == 0)
                    unsafeAtomicAdd(&cnt[g], (float)(np - p));
            }
            p = np;
        }
        __syncthreads();
    }
}

// ---------------- embedding gather + layer1, output tiled T ----------------
__global__ __launch_bounds__(256) void embed_l1_kernel(
    const int* __restrict__ node_ids, const float* __restrict__ emb,
    const float* __restrict__ Ws, const float* __restrict__ Cv,
    float* __restrict__ T)
{
    int n = blockIdx.x * 256 + threadIdx.x;
    if (n >= NN) return;
    long nid = node_ids[n];
    const float4* e4 = (const float4*)(emb + nid * 128);
    float a[64];
#pragma unroll
    for (int j = 0; j < 64; j++) a[j] = Cv[j];
#pragma unroll 8
    for (int q = 0; q < 32; q++) {
        float4 t = e4[q];
        const float* w = Ws + q * 256;
#pragma unroll
        for (int j = 0; j < 64; j++) a[j] += t.x * w[j];
#pragma unroll
        for (int j = 0; j < 64; j++) a[j] += t.y * w[64 + j];
#pragma unroll
        for (int j = 0; j < 64; j++) a[j] += t.z * w[128 + j];
#pragma unroll
        for (int j = 0; j < 64; j++) a[j] += t.w * w[192 + j];
    }
    int tile = n >> 7, i = n & 127;
    float* base = T + (long)tile * 8192 + i;
#pragma unroll
    for (int j = 0; j < 64; j++) base[j * 128] = fmaxf(a[j], 0.f);
}

// ---------------- readout + softmax ----------------
__global__ void final_kernel(
    const float* __restrict__ pooled, const float* __restrict__ cnt,
    const float* __restrict__ linW, const float* __restrict__ linb,
    float* __restrict__ outp)
{
    int g = threadIdx.x;
    if (g >= GG) return;
    float z0 = 0.f, z1 = 0.f;
    float c = cnt[g];
    for (int l = 0; l < 4; l++) {
        const float* p = pooled + (long)l * GG * 64 + (long)g * 64;
        const float* W = linW + l * 128;
        float bscale = (l == 0) ? c : 1.f;   // layer0 bias summed per node; others once
        float s0 = linb[l * 2 + 0] * bscale;
        float s1 = linb[l * 2 + 1] * bscale;
        for (int k = 0; k < 64; k++) {
            float pk = p[k];
            s0 += pk * W[k * 2 + 0];
            s1 += pk * W[k * 2 + 1];
        }
        z0 += s0; z1 += s1;
    }
    float mx = fmaxf(z0, z1);
    float e0 = expf(z0 - mx), e1 = expf(z1 - mx);
    float inv = 1.f / (e0 + e1);
    outp[g * 2 + 0] = e0 * inv;
    outp[g * 2 + 1] = e1 * inv;
}

extern "C" void kernel_launch(void* const* d_in, const int* in_sizes, int n_in,
                              void* d_out, int out_size, void* d_ws, size_t ws_size,
                              hipStream_t stream) {
    const int*   node_ids = (const int*)d_in[0];
    const int*   edges    = (const int*)d_in[1];
    const int*   batch    = (const int*)d_in[2];
    const float* emb      = (const float*)d_in[3];
    const float* fh_W1 = (const float*)d_in[4];
    const float* fh_b1 = (const float*)d_in[5];
    const float* fh_g1 = (const float*)d_in[6];
    const float* fh_bt1 = (const float*)d_in[7];
    const float* fh_m1 = (const float*)d_in[8];
    const float* fh_v1 = (const float*)d_in[9];
    const float* fh_W2 = (const float*)d_in[10];
    const float* fh_b2 = (const float*)d_in[11];
    const float* fh_g2 = (const float*)d_in[12];
    const float* fh_bt2 = (const float*)d_in[13];
    const float* fh_m2 = (const float*)d_in[14];
    const float* fh_v2 = (const float*)d_in[15];
    const float* cW1 = (const float*)d_in[16];
    const float* cb1 = (const float*)d_in[17];
    const float* cg1 = (const float*)d_in[18];
    const float* cbt1 = (const float*)d_in[19];
    const float* cm1 = (const float*)d_in[20];
    const float* cv1 = (const float*)d_in[21];
    const float* cW2 = (const float*)d_in[22];
    const float* cb2 = (const float*)d_in[23];
    const float* cg2 = (const float*)d_in[24];
    const float* cbt2 = (const float*)d_in[25];
    const float* cm2 = (const float*)d_in[26];
    const float* cv2 = (const float*)d_in[27];
    const float* linW = (const float*)d_in[28];
    const float* linb = (const float*)d_in[29];

    float* ws = (float*)d_ws;
    int*   cursor = (int*)(ws + CUR_OFF);
    int*   col    = (int*)(ws + COL_OFF);
    int*   bsum   = (int*)(ws + BSUM_OFF);
    float* Tt     = ws + T_OFF;

    prep_kernel<<<8, 256, 0, stream>>>(
        fh_W1, fh_b1, fh_g1, fh_bt1, fh_m1, fh_v1,
        fh_W2, fh_b2, fh_g2, fh_bt2, fh_m2, fh_v2,
        cW1, cb1, cg1, cbt1, cm1, cv1,
        cW2, cb2, cg2, cbt2, cm2, cv2, ws);

    hipMemsetAsync(ws + POOL_OFF, 0, (4L * GG * 64 + GG) * sizeof(float), stream);
    hipMemsetAsync(cursor, 0, NN * sizeof(int), stream);

    // CSR build (dst-indexed, single-pass fill)
    hist_kernel<<<(EE + 255) / 256, 256, 0, stream>>>(edges, cursor);
    scan_pass1<<<SCAN_NBLK, SCAN_BLK, 0, stream>>>(cursor, bsum);
    scan_pass2<<<1, 128, 0, stream>>>(bsum);
    scan_pass3<<<SCAN_NBLK, SCAN_BLK, 0, stream>>>(cursor, bsum);
    fill_kernel<<<(EE + 255) / 256, 256, 0, stream>>>(edges, cursor, col);

    const int MBLK = (NT * 128) / 256;   // 391

    // first MLP: emb + L1 -> T (tiled), then L2: T -> x + stage-0 pool (with cnt)
    embed_l1_kernel<<<MBLK, 256, 0, stream>>>(
        node_ids, emb, ws + WT1_OFF, ws + C1_OFF, Tt);
    mlp_t_out_pool_kernel<<<MBLK, 256, 0, stream>>>(
        Tt, ws + WT2_OFF, ws + C2_OFF, batch, ws + X_OFF,
        ws + POOL_OFF, ws + CNT_OFF);

    for (int l = 0; l < 3; l++) {
        gather_t_kernel<<<NT * 2, 256, 0, stream>>>(ws + X_OFF, cursor, col, Tt);
        mlp_t_kernel<<<MBLK, 256, 0, stream>>>(
            Tt, ws + WTC1_OFF + l * 4096, ws + CC1_OFF + l * 64);
        mlp_t_out_pool_kernel<<<MBLK, 256, 0, stream>>>(
            Tt, ws + WTC2_OFF + l * 4096, ws + CC2_OFF + l * 64, batch, ws + X_OFF,
            ws + POOL_OFF + (long)(l + 1) * GG * 64, nullptr);
    }

    final_kernel<<<1, 128, 0, stream>>>(
        ws + POOL_OFF, ws + CNT_OFF, linW, linb, (float*)d_out);
}